// Round 7
// baseline (520.423 us; speedup 1.0000x reference)
//
#include <hip/hip_runtime.h>
#include <hip/hip_bf16.h>
#include <stdint.h>

// MultiHeadAttention: B=2, S=2048, D=1024, H=16, dk=64
// d_in (fp32): Q,K,V, mask(int32), Wq,bq,Wk,bk,Wv,bv,Wo,bo
// d_out (FP32): out [2,2048,1024] then attn [2,16,2048,2048], concatenated.
// R7: hw bf16 cvt (v_cvt_pk_bf16_f32) + direct-reg fp32 attn stores +
//     gemm_out 64x128 tile (2 blocks/CU).

typedef __attribute__((ext_vector_type(8))) short bf16x8;
typedef __attribute__((ext_vector_type(4))) float f32x4;
typedef unsigned long long u64;

#define MFMA16(a, b, c) __builtin_amdgcn_mfma_f32_16x16x32_bf16((a), (b), (c), 0, 0, 0)

__device__ __forceinline__ float bf2f(short s) {
  union { float f; unsigned u; } x;
  x.u = ((unsigned)(unsigned short)s) << 16;
  return x.f;
}
__device__ __forceinline__ short f2bf(float f) {  // RTNE via hw cvt
  union { __hip_bfloat16 h; short s; } u;
  u.h = __float2bfloat16(f);
  return u.s;
}
__device__ __forceinline__ bf16x8 pack8(float4 a, float4 b) {
  union { __hip_bfloat162 h[4]; bf16x8 v; } u;
  u.h[0] = __float22bfloat162_rn(make_float2(a.x, a.y));
  u.h[1] = __float22bfloat162_rn(make_float2(a.z, a.w));
  u.h[2] = __float22bfloat162_rn(make_float2(b.x, b.y));
  u.h[3] = __float22bfloat162_rn(make_float2(b.z, b.w));
  return u.v;
}
__device__ __forceinline__ uint2 pack4(float p0, float p1, float p2, float p3) {
  union { __hip_bfloat162 h[2]; uint2 v; } u;
  u.h[0] = __float22bfloat162_rn(make_float2(p0, p1));
  u.h[1] = __float22bfloat162_rn(make_float2(p2, p3));
  return u.v;
}

// ---------------- diagnostic sentinel --------------------------------------
__global__ __launch_bounds__(256) void sentinel_fill(float* __restrict__ out,
                                                     float v, int n) {
  int i = blockIdx.x * 256 + threadIdx.x;
  if (i < n) out[i] = v;
}

// ---------------- mask bit-pack: [B,S,S] int32 -> [B,S,S/64] u64 ----------
__global__ __launch_bounds__(256) void pack_mask(const int* __restrict__ m,
                                                 u64* __restrict__ p) {
  long idx = (long)blockIdx.x * 256 + threadIdx.x;
  u64 b = __ballot(m[idx] != 0);
  if ((threadIdx.x & 63) == 0) p[idx >> 6] = b;
}

// ------------- merged QKV projection: 3 GEMMs in one launch ----------------
struct QkvPtrs {
  const float *A0, *A1, *A2;
  const float *W0, *W1, *W2;
  const float *c0, *c1, *c2;
  short *o0, *o1, *o2;
};
__global__ __launch_bounds__(256) void gemm_qkv(QkvPtrs p) {
  __shared__ short As[128 * 32];
  __shared__ short Bs[128 * 32];
  const int z = blockIdx.z;
  const float* Af = z == 0 ? p.A0 : (z == 1 ? p.A1 : p.A2);
  const float* W = z == 0 ? p.W0 : (z == 1 ? p.W1 : p.W2);
  const float* bias = z == 0 ? p.c0 : (z == 1 ? p.c1 : p.c2);
  short* outs = z == 0 ? p.o0 : (z == 1 ? p.o1 : p.o2);

  const int tid = threadIdx.x;
  const int lane = tid & 63;
  const int wid = tid >> 6;
  const int wr = wid >> 1, wc = wid & 1;
  const int m0 = blockIdx.x * 128;
  const int n0 = blockIdx.y * 128;

  const int srow = tid >> 1;
  const int scol = (tid & 1) << 4;
  const long aoff = (long)(m0 + srow) * 1024 + scol;
  const float* Wg = W + (long)(n0 + srow) * 1024 + scol;
  short* sA = As + srow * 32 + scol;
  short* sB = Bs + srow * 32 + scol;

  f32x4 acc[4][4] = {};
  const int fr = lane & 15;
  const int fc = (lane >> 4) << 3;

  for (int k0 = 0; k0 < 1024; k0 += 32) {
    __syncthreads();
    float4 x0 = *(const float4*)(Af + aoff + k0);
    float4 x1 = *(const float4*)(Af + aoff + k0 + 4);
    float4 x2 = *(const float4*)(Af + aoff + k0 + 8);
    float4 x3 = *(const float4*)(Af + aoff + k0 + 12);
    float4 w0 = *(const float4*)(Wg + k0);
    float4 w1 = *(const float4*)(Wg + k0 + 4);
    float4 w2 = *(const float4*)(Wg + k0 + 8);
    float4 w3 = *(const float4*)(Wg + k0 + 12);
    *(bf16x8*)sA = pack8(x0, x1);
    *(bf16x8*)(sA + 8) = pack8(x2, x3);
    *(bf16x8*)sB = pack8(w0, w1);
    *(bf16x8*)(sB + 8) = pack8(w2, w3);
    __syncthreads();
    bf16x8 a[4], b[4];
#pragma unroll
    for (int i = 0; i < 4; ++i)
      a[i] = *(const bf16x8*)&As[(wr * 64 + i * 16 + fr) * 32 + fc];
#pragma unroll
    for (int i = 0; i < 4; ++i)
      b[i] = *(const bf16x8*)&Bs[(wc * 64 + i * 16 + fr) * 32 + fc];
#pragma unroll
    for (int i = 0; i < 4; ++i)
#pragma unroll
      for (int j = 0; j < 4; ++j)
        acc[i][j] = MFMA16(a[i], b[j], acc[i][j]);
  }

#pragma unroll
  for (int i = 0; i < 4; ++i) {
    const int row0 = m0 + wr * 64 + i * 16 + (lane >> 4) * 4;
#pragma unroll
    for (int j = 0; j < 4; ++j) {
      const int col = n0 + wc * 64 + j * 16 + fr;
      const float bv = bias[col];
      const int h = col >> 6, dd = col & 63;
      if (z != 2) {
#pragma unroll
        for (int r = 0; r < 4; ++r) {
          const int m = row0 + r;
          const long o = (((long)(m >> 11) * 16 + h) * 2048 + (m & 2047)) * 64 + dd;
          outs[o] = f2bf(acc[i][j][r] + bv);
        }
      } else {
        const long o = (((long)(row0 >> 11) * 16 + h) * 64 + dd) * 2048 + (row0 & 2047);
        *(uint2*)&outs[o] = pack4(acc[i][j][0] + bv, acc[i][j][1] + bv,
                                  acc[i][j][2] + bv, acc[i][j][3] + bv);
      }
    }
  }
}

// ---------------- final GEMM: out = ctx(bf16) @ Wo^T + bo (fp32 out) -------
// 64x128 tile, grid(64,8) = 2 blocks/CU.
__global__ __launch_bounds__(256) void gemm_out(const short* __restrict__ Ab,
                                                const float* __restrict__ W,
                                                const float* __restrict__ bias,
                                                float* __restrict__ outf) {
  __shared__ short As[64 * 32];
  __shared__ short Bs[128 * 32];
  const int tid = threadIdx.x;
  const int lane = tid & 63;
  const int wid = tid >> 6;
  const int wr = wid >> 1, wc = wid & 1;
  const int m0 = blockIdx.x * 64;
  const int n0 = blockIdx.y * 128;

  const int arow_s = tid >> 2;          // 0..63
  const int acol_s = (tid & 3) << 3;    // 0,8,16,24
  const long aoff = (long)(m0 + arow_s) * 1024 + acol_s;
  const int brow_s = tid >> 1;          // 0..127
  const int bcol_s = (tid & 1) << 4;
  const float* Wg = W + (long)(n0 + brow_s) * 1024 + bcol_s;
  short* sA = As + arow_s * 32 + acol_s;
  short* sB = Bs + brow_s * 32 + bcol_s;

  f32x4 acc[2][4] = {};
  const int fr = lane & 15;
  const int fc = (lane >> 4) << 3;

  for (int k0 = 0; k0 < 1024; k0 += 32) {
    __syncthreads();
    bf16x8 va = *(const bf16x8*)(Ab + aoff + k0);
    float4 w0 = *(const float4*)(Wg + k0);
    float4 w1 = *(const float4*)(Wg + k0 + 4);
    float4 w2 = *(const float4*)(Wg + k0 + 8);
    float4 w3 = *(const float4*)(Wg + k0 + 12);
    *(bf16x8*)sA = va;
    *(bf16x8*)sB = pack8(w0, w1);
    *(bf16x8*)(sB + 8) = pack8(w2, w3);
    __syncthreads();
    bf16x8 a[2], b[4];
#pragma unroll
    for (int i = 0; i < 2; ++i)
      a[i] = *(const bf16x8*)&As[(wr * 32 + i * 16 + fr) * 32 + fc];
#pragma unroll
    for (int j = 0; j < 4; ++j)
      b[j] = *(const bf16x8*)&Bs[(wc * 64 + j * 16 + fr) * 32 + fc];
#pragma unroll
    for (int i = 0; i < 2; ++i)
#pragma unroll
      for (int j = 0; j < 4; ++j)
        acc[i][j] = MFMA16(a[i], b[j], acc[i][j]);
  }

#pragma unroll
  for (int i = 0; i < 2; ++i) {
    const int row0 = m0 + wr * 32 + i * 16 + (lane >> 4) * 4;
#pragma unroll
    for (int j = 0; j < 4; ++j) {
      const int col = n0 + wc * 64 + j * 16 + fr;
      const float bv = bias[col];
#pragma unroll
      for (int r = 0; r < 4; ++r)
        outf[(long)(row0 + r) * 1024 + col] = acc[i][j][r] + bv;
    }
  }
}

// ------------- softmax denominators (swapped QK^T) -------------------------
__global__ __launch_bounds__(256) void attn_denom(const short* __restrict__ qw,
                                                  const short* __restrict__ kw,
                                                  const u64* __restrict__ pm,
                                                  float* __restrict__ inv_l) {
  const int lane = threadIdx.x & 63;
  const int wid = threadIdx.x >> 6;
  const int bh = blockIdx.y;        // b*16+h
  const int mb = bh & 1;            // torch tile quirk: mask batch = (b*H+h)%B
  const int q0 = blockIdx.x * 128 + wid * 32;
  const int fr = lane & 15;
  const int fg = lane >> 4;

  bf16x8 aq[2][2];
#pragma unroll
  for (int mi = 0; mi < 2; ++mi) {
    const short* qb = qw + ((long)bh * 2048 + q0 + mi * 16 + fr) * 64 + fg * 8;
#pragma unroll
    for (int ks = 0; ks < 2; ++ks) aq[mi][ks] = *(const bf16x8*)(qb + ks * 32);
  }
  float rs[2] = {0.f, 0.f};
  const u64* mbase = pm + ((long)mb * 2048 + q0) * 32;
  const short* kbase = kw + (long)bh * 2048 * 64;

  for (int kt = 0; kt < 32; ++kt) {
    u64 mrow[2];
#pragma unroll
    for (int mi = 0; mi < 2; ++mi)
      mrow[mi] = mbase[(mi * 16 + fr) * 32 + kt];
#pragma unroll
    for (int ni = 0; ni < 4; ++ni) {
      const short* kb = kbase + ((long)kt * 64 + ni * 16 + fr) * 64 + fg * 8;
      bf16x8 b0 = *(const bf16x8*)kb;
      bf16x8 b1 = *(const bf16x8*)(kb + 32);
      const int kb0 = ni * 16 + fg * 4;
#pragma unroll
      for (int mi = 0; mi < 2; ++mi) {
        // swapped: lane holds q-row (mi*16+fr), k-cols kb0..kb0+3
        f32x4 s = {0.f, 0.f, 0.f, 0.f};
        s = MFMA16(b0, aq[mi][0], s);
        s = MFMA16(b1, aq[mi][1], s);
#pragma unroll
        for (int r = 0; r < 4; ++r)
          if ((mrow[mi] >> (kb0 + r)) & 1ULL) rs[mi] += __expf(s[r] * 0.125f);
      }
    }
  }
#pragma unroll
  for (int mi = 0; mi < 2; ++mi) {
    float v = rs[mi];
    v += __shfl_xor(v, 16);
    v += __shfl_xor(v, 32);
    if (lane < 16)
      inv_l[(long)bh * 2048 + q0 + mi * 16 + lane] = 1.0f / v;
  }
}

// ------------- attn (fp32, direct reg stores) + ctx = attn @ v -------------
__global__ __launch_bounds__(256) void attn_av(
    const short* __restrict__ qw, const short* __restrict__ kw,
    const short* __restrict__ vtw, const u64* __restrict__ pm,
    const float* __restrict__ inv_l, float* __restrict__ attn,
    short* __restrict__ ctx) {
  __shared__ short P[4][32 * 72];  // per-wave P tile (PV A-frags only)
  const int lane = threadIdx.x & 63;
  const int wid = threadIdx.x >> 6;
  const int bh = blockIdx.y;
  const int mb = bh & 1;
  const int q0 = blockIdx.x * 128 + wid * 32;
  const int fr = lane & 15;
  const int fg = lane >> 4;
  short* Pw = P[wid];

  bf16x8 aq[2][2];
#pragma unroll
  for (int mi = 0; mi < 2; ++mi) {
    const short* qb = qw + ((long)bh * 2048 + q0 + mi * 16 + fr) * 64 + fg * 8;
#pragma unroll
    for (int ks = 0; ks < 2; ++ks) aq[mi][ks] = *(const bf16x8*)(qb + ks * 32);
  }
  float il[2];
#pragma unroll
  for (int mi = 0; mi < 2; ++mi)
    il[mi] = inv_l[(long)bh * 2048 + q0 + mi * 16 + fr];  // coalesced

  f32x4 cacc[2][4] = {};
  const u64* mbase = pm + ((long)mb * 2048 + q0) * 32;
  const short* kbase = kw + (long)bh * 2048 * 64;
  const short* vbase = vtw + (long)bh * 64 * 2048;
  const long arow = (long)bh * 2048 + q0;

  for (int kt = 0; kt < 32; ++kt) {
    u64 mrow[2];
#pragma unroll
    for (int mi = 0; mi < 2; ++mi)
      mrow[mi] = mbase[(mi * 16 + fr) * 32 + kt];

    // swapped scores -> p: fp32 float4 direct to attn; bf16 uint2 to LDS
#pragma unroll
    for (int ni = 0; ni < 4; ++ni) {
      const short* kb = kbase + ((long)kt * 64 + ni * 16 + fr) * 64 + fg * 8;
      bf16x8 b0 = *(const bf16x8*)kb;
      bf16x8 b1 = *(const bf16x8*)(kb + 32);
      const int kb0 = ni * 16 + fg * 4;
#pragma unroll
      for (int mi = 0; mi < 2; ++mi) {
        f32x4 s = {0.f, 0.f, 0.f, 0.f};
        s = MFMA16(b0, aq[mi][0], s);
        s = MFMA16(b1, aq[mi][1], s);
        float p0 = ((mrow[mi] >> (kb0 + 0)) & 1ULL) ? __expf(s[0] * 0.125f) * il[mi] : 0.0f;
        float p1 = ((mrow[mi] >> (kb0 + 1)) & 1ULL) ? __expf(s[1] * 0.125f) * il[mi] : 0.0f;
        float p2 = ((mrow[mi] >> (kb0 + 2)) & 1ULL) ? __expf(s[2] * 0.125f) * il[mi] : 0.0f;
        float p3 = ((mrow[mi] >> (kb0 + 3)) & 1ULL) ? __expf(s[3] * 0.125f) * il[mi] : 0.0f;
        *(float4*)&attn[(arow + mi * 16 + fr) * 2048 + kt * 64 + kb0] =
            make_float4(p0, p1, p2, p3);
        *(uint2*)&Pw[(mi * 16 + fr) * 72 + kb0] = pack4(p0, p1, p2, p3);
      }
    }

    // ctx += P(32x64) @ V(64x64)   (same-wave LDS dep; ds ops in-order)
#pragma unroll
    for (int ks = 0; ks < 2; ++ks) {
      bf16x8 pa[2];
#pragma unroll
      for (int mi = 0; mi < 2; ++mi)
        pa[mi] = *(const bf16x8*)&Pw[(mi * 16 + fr) * 72 + ks * 32 + fg * 8];
#pragma unroll
      for (int ni = 0; ni < 4; ++ni) {
        bf16x8 bv = *(const bf16x8*)(vbase + ((long)(ni * 16 + fr)) * 2048 +
                                     kt * 64 + ks * 32 + fg * 8);
#pragma unroll
        for (int mi = 0; mi < 2; ++mi)
          cacc[mi][ni] = MFMA16(pa[mi], bv, cacc[mi][ni]);
      }
    }
  }

  // ctx: [B,S,D] row-major (bf16) for the final GEMM
  const int b_ = bh >> 4, h_ = bh & 15;
#pragma unroll
  for (int mi = 0; mi < 2; ++mi)
#pragma unroll
    for (int ni = 0; ni < 4; ++ni)
#pragma unroll
      for (int r = 0; r < 4; ++r)
        ctx[((long)b_ * 2048 + q0 + mi * 16 + fg * 4 + r) * 1024 + h_ * 64 +
            ni * 16 + fr] = f2bf(cacc[mi][ni][r]);
}

extern "C" void kernel_launch(void* const* d_in, const int* in_sizes, int n_in,
                              void* d_out, int out_size, void* d_ws,
                              size_t ws_size, hipStream_t stream) {
  float* out_o = (float*)d_out;

  const bool sizes_ok =
      (n_in == 12) && in_sizes[0] == 4194304 && in_sizes[1] == 4194304 &&
      in_sizes[2] == 4194304 && in_sizes[3] == 8388608 &&
      in_sizes[4] == 1048576 && in_sizes[5] == 1024 &&
      in_sizes[10] == 1048576 && in_sizes[11] == 1024 &&
      out_size == (2 * 2048 * 1024 + 2 * 16 * 2048 * 2048);
  const size_t WS_NEED = 34865152;
  if (!sizes_ok) {
    sentinel_fill<<<dim3(16384), 256, 0, stream>>>(out_o, 555.0f, 4194304);
    return;
  }
  if (ws_size < WS_NEED) {
    sentinel_fill<<<dim3(16384), 256, 0, stream>>>(out_o, 777.0f, 4194304);
    return;
  }

  const float* Q = (const float*)d_in[0];
  const float* K = (const float*)d_in[1];
  const float* V = (const float*)d_in[2];
  const int* mask = (const int*)d_in[3];
  const float* Wq = (const float*)d_in[4];
  const float* bq = (const float*)d_in[5];
  const float* Wk = (const float*)d_in[6];
  const float* bk = (const float*)d_in[7];
  const float* Wv = (const float*)d_in[8];
  const float* bv = (const float*)d_in[9];
  const float* Wo = (const float*)d_in[10];
  const float* bo = (const float*)d_in[11];

  short* qws = (short*)d_ws;               // [2,16,2048,64] bf16
  short* kws = qws + 4194304;              // [2,16,2048,64] bf16
  short* vtws = kws + 4194304;             // [2,16,64,2048] bf16 (v^T)
  short* ctxws = vtws + 4194304;           // [2,2048,1024]  bf16
  float* invl = (float*)(ctxws + 4194304); // [2,16,2048]    f32
  u64* pmask = (u64*)(invl + 65536);       // [2,2048,32]    u64

  float* out_attn = out_o + 2 * 2048 * 1024;

  pack_mask<<<dim3(2 * 2048 * 2048 / 256), 256, 0, stream>>>(mask, pmask);
  QkvPtrs p = {Q, K, V, Wq, Wk, Wv, bq, bk, bv, qws, kws, vtws};
  gemm_qkv<<<dim3(32, 8, 3), 256, 0, stream>>>(p);
  attn_denom<<<dim3(16, 32), 256, 0, stream>>>(qws, kws, pmask, invl);
  attn_av<<<dim3(16, 32), 256, 0, stream>>>(qws, kws, vtws, pmask, invl,
                                            out_attn, ctxws);
  gemm_out<<<dim3(64, 8), 256, 0, stream>>>(ctxws, Wo, bo, out_o);
}

// Round 8
// 468.934 us; speedup vs baseline: 1.1098x; 1.1098x over previous
//
#include <hip/hip_runtime.h>
#include <stdint.h>

// MultiHeadAttention: B=2, S=2048, D=1024, H=16, dk=64
// d_in (fp32): Q,K,V, mask(int32), Wq,bq,Wk,bk,Wv,bv,Wo,bo
// d_out (FP32): out [2,2048,1024] then attn [2,16,2048,2048], concatenated.
// R8: revert to R6 baseline (478us) + fuse denom into attn (one kernel,
//     denominators in registers) + bh-major grid for XCD K-locality.

typedef __attribute__((ext_vector_type(8))) short bf16x8;
typedef __attribute__((ext_vector_type(4))) float f32x4;
typedef unsigned long long u64;

#define MFMA16(a, b, c) __builtin_amdgcn_mfma_f32_16x16x32_bf16((a), (b), (c), 0, 0, 0)

__device__ __forceinline__ float bf2f(short s) {
  union { float f; unsigned u; } x;
  x.u = ((unsigned)(unsigned short)s) << 16;
  return x.f;
}
__device__ __forceinline__ short f2bf(float f) {  // RTNE
  union { float f; unsigned u; } x;
  x.f = f;
  unsigned r = x.u + 0x7fffu + ((x.u >> 16) & 1u);
  return (short)(r >> 16);
}
__device__ __forceinline__ bf16x8 pack8(float4 a, float4 b) {
  union { short s[8]; bf16x8 v; } u;
  u.s[0] = f2bf(a.x); u.s[1] = f2bf(a.y); u.s[2] = f2bf(a.z); u.s[3] = f2bf(a.w);
  u.s[4] = f2bf(b.x); u.s[5] = f2bf(b.y); u.s[6] = f2bf(b.z); u.s[7] = f2bf(b.w);
  return u.v;
}

// ---------------- diagnostic sentinel --------------------------------------
__global__ __launch_bounds__(256) void sentinel_fill(float* __restrict__ out,
                                                     float v, int n) {
  int i = blockIdx.x * 256 + threadIdx.x;
  if (i < n) out[i] = v;
}

// ---------------- mask bit-pack: [B,S,S] int32 -> [B,S,S/64] u64 ----------
__global__ __launch_bounds__(256) void pack_mask(const int* __restrict__ m,
                                                 u64* __restrict__ p) {
  long idx = (long)blockIdx.x * 256 + threadIdx.x;
  u64 b = __ballot(m[idx] != 0);
  if ((threadIdx.x & 63) == 0) p[idx >> 6] = b;
}

// ------------- merged QKV projection: 3 GEMMs in one launch ----------------
struct QkvPtrs {
  const float *A0, *A1, *A2;
  const float *W0, *W1, *W2;
  const float *c0, *c1, *c2;
  short *o0, *o1, *o2;
};
__global__ __launch_bounds__(256) void gemm_qkv(QkvPtrs p) {
  __shared__ short As[128 * 32];
  __shared__ short Bs[128 * 32];
  const int z = blockIdx.z;
  const float* Af = z == 0 ? p.A0 : (z == 1 ? p.A1 : p.A2);
  const float* W = z == 0 ? p.W0 : (z == 1 ? p.W1 : p.W2);
  const float* bias = z == 0 ? p.c0 : (z == 1 ? p.c1 : p.c2);
  short* outs = z == 0 ? p.o0 : (z == 1 ? p.o1 : p.o2);

  const int tid = threadIdx.x;
  const int lane = tid & 63;
  const int wid = tid >> 6;
  const int wr = wid >> 1, wc = wid & 1;
  const int m0 = blockIdx.x * 128;
  const int n0 = blockIdx.y * 128;

  const int srow = tid >> 1;
  const int scol = (tid & 1) << 4;
  const long aoff = (long)(m0 + srow) * 1024 + scol;
  const float* Wg = W + (long)(n0 + srow) * 1024 + scol;
  short* sA = As + srow * 32 + scol;
  short* sB = Bs + srow * 32 + scol;

  f32x4 acc[4][4] = {};
  const int fr = lane & 15;
  const int fc = (lane >> 4) << 3;

  for (int k0 = 0; k0 < 1024; k0 += 32) {
    __syncthreads();
    float4 x0 = *(const float4*)(Af + aoff + k0);
    float4 x1 = *(const float4*)(Af + aoff + k0 + 4);
    float4 x2 = *(const float4*)(Af + aoff + k0 + 8);
    float4 x3 = *(const float4*)(Af + aoff + k0 + 12);
    float4 w0 = *(const float4*)(Wg + k0);
    float4 w1 = *(const float4*)(Wg + k0 + 4);
    float4 w2 = *(const float4*)(Wg + k0 + 8);
    float4 w3 = *(const float4*)(Wg + k0 + 12);
    *(bf16x8*)sA = pack8(x0, x1);
    *(bf16x8*)(sA + 8) = pack8(x2, x3);
    *(bf16x8*)sB = pack8(w0, w1);
    *(bf16x8*)(sB + 8) = pack8(w2, w3);
    __syncthreads();
    bf16x8 a[4], b[4];
#pragma unroll
    for (int i = 0; i < 4; ++i)
      a[i] = *(const bf16x8*)&As[(wr * 64 + i * 16 + fr) * 32 + fc];
#pragma unroll
    for (int i = 0; i < 4; ++i)
      b[i] = *(const bf16x8*)&Bs[(wc * 64 + i * 16 + fr) * 32 + fc];
#pragma unroll
    for (int i = 0; i < 4; ++i)
#pragma unroll
      for (int j = 0; j < 4; ++j)
        acc[i][j] = MFMA16(a[i], b[j], acc[i][j]);
  }

#pragma unroll
  for (int i = 0; i < 4; ++i) {
    const int row0 = m0 + wr * 64 + i * 16 + (lane >> 4) * 4;
#pragma unroll
    for (int j = 0; j < 4; ++j) {
      const int col = n0 + wc * 64 + j * 16 + fr;
      const float bv = bias[col];
      const int h = col >> 6, dd = col & 63;
      if (z != 2) {
#pragma unroll
        for (int r = 0; r < 4; ++r) {
          const int m = row0 + r;
          const long o = (((long)(m >> 11) * 16 + h) * 2048 + (m & 2047)) * 64 + dd;
          outs[o] = f2bf(acc[i][j][r] + bv);
        }
      } else {
        const long o = (((long)(row0 >> 11) * 16 + h) * 64 + dd) * 2048 + (row0 & 2047);
        union { unsigned short us[4]; uint2 v; } pk;
#pragma unroll
        for (int r = 0; r < 4; ++r) pk.us[r] = (unsigned short)f2bf(acc[i][j][r] + bv);
        *(uint2*)&outs[o] = pk.v;
      }
    }
  }
}

// ---------------- final GEMM: out = ctx(bf16) @ Wo^T + bo (fp32 out) -------
__global__ __launch_bounds__(256) void gemm_out(const short* __restrict__ Ab,
                                                const float* __restrict__ W,
                                                const float* __restrict__ bias,
                                                float* __restrict__ outf) {
  __shared__ short As[128 * 32];
  __shared__ short Bs[128 * 32];
  const int tid = threadIdx.x;
  const int lane = tid & 63;
  const int wid = tid >> 6;
  const int wr = wid >> 1, wc = wid & 1;
  const int m0 = blockIdx.x * 128;
  const int n0 = blockIdx.y * 128;

  const int srow = tid >> 1;
  const int scol = (tid & 1) << 4;
  const long aoff = (long)(m0 + srow) * 1024 + scol;
  const float* Wg = W + (long)(n0 + srow) * 1024 + scol;
  short* sA = As + srow * 32 + scol;
  short* sB = Bs + srow * 32 + scol;

  f32x4 acc[4][4] = {};
  const int fr = lane & 15;
  const int fc = (lane >> 4) << 3;

  for (int k0 = 0; k0 < 1024; k0 += 32) {
    __syncthreads();
    bf16x8 va0 = *(const bf16x8*)(Ab + aoff + k0);
    bf16x8 va1 = *(const bf16x8*)(Ab + aoff + k0 + 8);
    float4 w0 = *(const float4*)(Wg + k0);
    float4 w1 = *(const float4*)(Wg + k0 + 4);
    float4 w2 = *(const float4*)(Wg + k0 + 8);
    float4 w3 = *(const float4*)(Wg + k0 + 12);
    *(bf16x8*)sA = va0;
    *(bf16x8*)(sA + 8) = va1;
    *(bf16x8*)sB = pack8(w0, w1);
    *(bf16x8*)(sB + 8) = pack8(w2, w3);
    __syncthreads();
    bf16x8 a[4], b[4];
#pragma unroll
    for (int i = 0; i < 4; ++i)
      a[i] = *(const bf16x8*)&As[(wr * 64 + i * 16 + fr) * 32 + fc];
#pragma unroll
    for (int i = 0; i < 4; ++i)
      b[i] = *(const bf16x8*)&Bs[(wc * 64 + i * 16 + fr) * 32 + fc];
#pragma unroll
    for (int i = 0; i < 4; ++i)
#pragma unroll
      for (int j = 0; j < 4; ++j)
        acc[i][j] = MFMA16(a[i], b[j], acc[i][j]);
  }

#pragma unroll
  for (int i = 0; i < 4; ++i) {
    const int row0 = m0 + wr * 64 + i * 16 + (lane >> 4) * 4;
#pragma unroll
    for (int j = 0; j < 4; ++j) {
      const int col = n0 + wc * 64 + j * 16 + fr;
      const float bv = bias[col];
#pragma unroll
      for (int r = 0; r < 4; ++r)
        outf[(long)(row0 + r) * 1024 + col] = acc[i][j][r] + bv;
    }
  }
}

// ------------- fused attention: denom (regs) + attn write + PV -------------
// grid (32 bh, 16 qtile): linear id = bh + 32*qt -> XCD = bh%8, so all
// q-tiles of one (b,h) share an XCD and K stays L2-resident for phase 2.
__global__ __launch_bounds__(256) void attn_fused(
    const short* __restrict__ qw, const short* __restrict__ kw,
    const short* __restrict__ vtw, const u64* __restrict__ pm,
    float* __restrict__ attn, short* __restrict__ ctx) {
  __shared__ short P[4][32 * 72];  // per-wave P tile, +8 pad breaks bank conflict
  const int lane = threadIdx.x & 63;
  const int wid = threadIdx.x >> 6;
  const int bh = blockIdx.x;
  const int mb = bh & 1;  // torch tile quirk: mask batch = (b*H+h)%B
  const int q0 = blockIdx.y * 128 + wid * 32;
  const int fr = lane & 15;
  const int fg = lane >> 4;
  short* Pw = P[wid];

  bf16x8 aq[2][2];
#pragma unroll
  for (int mi = 0; mi < 2; ++mi) {
    const short* qb = qw + ((long)bh * 2048 + q0 + mi * 16 + fr) * 64 + fg * 8;
#pragma unroll
    for (int ks = 0; ks < 2; ++ks) aq[mi][ks] = *(const bf16x8*)(qb + ks * 32);
  }

  const u64* mbase = pm + ((long)mb * 2048 + q0) * 32;
  const short* kbase = kw + (long)bh * 2048 * 64;
  const short* vbase = vtw + (long)bh * 64 * 2048;
  const long arow = (long)bh * 2048 + q0;

  // ---- phase 1: denominators (swapped QK^T; lane holds q-row mi*16+fr) ----
  float rs[2] = {0.f, 0.f};
  for (int kt = 0; kt < 32; ++kt) {
    u64 mrow[2];
#pragma unroll
    for (int mi = 0; mi < 2; ++mi)
      mrow[mi] = mbase[(mi * 16 + fr) * 32 + kt];
#pragma unroll
    for (int ni = 0; ni < 4; ++ni) {
      const short* kb = kbase + ((long)kt * 64 + ni * 16 + fr) * 64 + fg * 8;
      bf16x8 b0 = *(const bf16x8*)kb;
      bf16x8 b1 = *(const bf16x8*)(kb + 32);
      const int kb0 = ni * 16 + fg * 4;
#pragma unroll
      for (int mi = 0; mi < 2; ++mi) {
        f32x4 s = {0.f, 0.f, 0.f, 0.f};
        s = MFMA16(b0, aq[mi][0], s);
        s = MFMA16(b1, aq[mi][1], s);
#pragma unroll
        for (int r = 0; r < 4; ++r)
          if ((mrow[mi] >> (kb0 + r)) & 1ULL) rs[mi] += __expf(s[r] * 0.125f);
      }
    }
  }
  float il[2];
#pragma unroll
  for (int mi = 0; mi < 2; ++mi) {
    float v = rs[mi];
    v += __shfl_xor(v, 16);
    v += __shfl_xor(v, 32);
    il[mi] = 1.0f / v;  // denominator for q-row mi*16+fr, in-register
  }

  // ---- phase 2: p -> attn (fp32, LDS-staged coalesced) + ctx += P@V -------
  f32x4 cacc[2][4] = {};
  for (int kt = 0; kt < 32; ++kt) {
    u64 mrow[2];
#pragma unroll
    for (int mi = 0; mi < 2; ++mi)
      mrow[mi] = mbase[(mi * 16 + fr) * 32 + kt];

#pragma unroll
    for (int ni = 0; ni < 4; ++ni) {
      const short* kb = kbase + ((long)kt * 64 + ni * 16 + fr) * 64 + fg * 8;
      bf16x8 b0 = *(const bf16x8*)kb;
      bf16x8 b1 = *(const bf16x8*)(kb + 32);
      const int kb0 = ni * 16 + fg * 4;
#pragma unroll
      for (int mi = 0; mi < 2; ++mi) {
        f32x4 s = {0.f, 0.f, 0.f, 0.f};
        s = MFMA16(b0, aq[mi][0], s);
        s = MFMA16(b1, aq[mi][1], s);
        union { unsigned short us[4]; uint2 v; } pk;
#pragma unroll
        for (int r = 0; r < 4; ++r) {
          float p = ((mrow[mi] >> (kb0 + r)) & 1ULL)
                        ? __expf(s[r] * 0.125f) * il[mi]
                        : 0.0f;
          pk.us[r] = (unsigned short)f2bf(p);
        }
        *(uint2*)&Pw[(mi * 16 + fr) * 72 + kb0] = pk.v;
      }
    }

    // ctx += P(32x64) @ V(64x64)   (same-wave LDS dep; ds ops in-order)
#pragma unroll
    for (int ks = 0; ks < 2; ++ks) {
      bf16x8 pa[2];
#pragma unroll
      for (int mi = 0; mi < 2; ++mi)
        pa[mi] = *(const bf16x8*)&Pw[(mi * 16 + fr) * 72 + ks * 32 + fg * 8];
#pragma unroll
      for (int ni = 0; ni < 4; ++ni) {
        bf16x8 bv = *(const bf16x8*)(vbase + ((long)(ni * 16 + fr)) * 2048 +
                                     kt * 64 + ks * 32 + fg * 8);
#pragma unroll
        for (int mi = 0; mi < 2; ++mi)
          cacc[mi][ni] = MFMA16(pa[mi], bv, cacc[mi][ni]);
      }
    }

    // fp32 attn writeback: expand LDS bf16 -> float4, 4x256B segments/instr
#pragma unroll
    for (int c = 0; c < 8; ++c) {
      const int idx = c * 64 + lane;
      const int row = idx >> 4;
      const int col = (idx & 15) * 4;
      union { uint2 w; short s[4]; } v4;
      v4.w = *(const uint2*)&Pw[row * 72 + col];
      float4 f;
      f.x = bf2f(v4.s[0]); f.y = bf2f(v4.s[1]);
      f.z = bf2f(v4.s[2]); f.w = bf2f(v4.s[3]);
      *(float4*)&attn[(arow + row) * 2048 + kt * 64 + col] = f;
    }
  }

  // ctx: [B,S,D] row-major (bf16) for the final GEMM
  const int b_ = bh >> 4, h_ = bh & 15;
#pragma unroll
  for (int mi = 0; mi < 2; ++mi)
#pragma unroll
    for (int ni = 0; ni < 4; ++ni)
#pragma unroll
      for (int r = 0; r < 4; ++r)
        ctx[((long)b_ * 2048 + q0 + mi * 16 + fg * 4 + r) * 1024 + h_ * 64 +
            ni * 16 + fr] = f2bf(cacc[mi][ni][r]);
}

extern "C" void kernel_launch(void* const* d_in, const int* in_sizes, int n_in,
                              void* d_out, int out_size, void* d_ws,
                              size_t ws_size, hipStream_t stream) {
  float* out_o = (float*)d_out;

  const bool sizes_ok =
      (n_in == 12) && in_sizes[0] == 4194304 && in_sizes[1] == 4194304 &&
      in_sizes[2] == 4194304 && in_sizes[3] == 8388608 &&
      in_sizes[4] == 1048576 && in_sizes[5] == 1024 &&
      in_sizes[10] == 1048576 && in_sizes[11] == 1024 &&
      out_size == (2 * 2048 * 1024 + 2 * 16 * 2048 * 2048);
  const size_t WS_NEED = 34603008;  // 4x 8MB bf16 ws + pmask 1MB
  if (!sizes_ok) {
    sentinel_fill<<<dim3(16384), 256, 0, stream>>>(out_o, 555.0f, 4194304);
    return;
  }
  if (ws_size < WS_NEED) {
    sentinel_fill<<<dim3(16384), 256, 0, stream>>>(out_o, 777.0f, 4194304);
    return;
  }

  const float* Q = (const float*)d_in[0];
  const float* K = (const float*)d_in[1];
  const float* V = (const float*)d_in[2];
  const int* mask = (const int*)d_in[3];
  const float* Wq = (const float*)d_in[4];
  const float* bq = (const float*)d_in[5];
  const float* Wk = (const float*)d_in[6];
  const float* bk = (const float*)d_in[7];
  const float* Wv = (const float*)d_in[8];
  const float* bv = (const float*)d_in[9];
  const float* Wo = (const float*)d_in[10];
  const float* bo = (const float*)d_in[11];

  short* qws = (short*)d_ws;               // [2,16,2048,64] bf16
  short* kws = qws + 4194304;              // [2,16,2048,64] bf16
  short* vtws = kws + 4194304;             // [2,16,64,2048] bf16 (v^T)
  short* ctxws = vtws + 4194304;           // [2,2048,1024]  bf16
  u64* pmask = (u64*)(ctxws + 4194304);    // [2,2048,32]    u64

  float* out_attn = out_o + 2 * 2048 * 1024;

  pack_mask<<<dim3(2 * 2048 * 2048 / 256), 256, 0, stream>>>(mask, pmask);
  QkvPtrs p = {Q, K, V, Wq, Wk, Wv, bq, bk, bv, qws, kws, vtws};
  gemm_qkv<<<dim3(32, 8, 3), 256, 0, stream>>>(p);
  attn_fused<<<dim3(32, 16), 256, 0, stream>>>(qws, kws, vtws, pmask,
                                               out_attn, ctxws);
  gemm_out<<<dim3(32, 8), 256, 0, stream>>>(ctxws, Wo, bo, out_o);
}